// Round 2
// 126.971 us; speedup vs baseline: 1.0389x; 1.0389x over previous
//
#include <hip/hip_runtime.h>

#define UNITS 256
#define NB 501               // num buckets
#define STEPF 0.05f
#define LBF -17.0f
#define UBF 8.0f
#define RESIDUEF -17.05f     // LB - STEP
#define LOG2E 1.4426950408889634f

#define WLO 192              // hot-window low bucket (x < -7.45 is cold)
#define WSZ 256              // window [192,448); P(outside) ~ 1e-7 of elements
#define UPB 32               // units per block (was 64). LDS halves ->
                             // 2 blocks/CU, 32 waves/CU (occupancy 40->~80%).
                             // x-loads become 8x128B contiguous runs per wave
                             // (still >=2 aligned cache lines per segment).
#define PADF2 257            // LDS row stride in float2
#define THREADS 1024         // 16 waves; 2 blocks/CU (LDS 65792B each)
#define ROWS_PB 1024         // grid = 8 unit-tiles * 64 row-tiles = 512 blocks
#define CHUNKS 8             // 8 chunks of 128 rows; depth-4 register ring
#define RDEPTH 4

// native vector type for nontemporal builtin (HIP float4 is a class type,
// rejected by __builtin_nontemporal_store)
typedef float floatx4 __attribute__((ext_vector_type(4)));

// ---------------------------------------------------------------------------
// Kernel 1: full fused table -> d_ws (1.03 MB, L2/L3-resident).
//   w  = relu(v[u,j])
//   C  = STEP*excl_cumsum(w)[j] + RESIDUE + b[u] - j*STEP*w
//   store (C*log2e, w*log2e):  sigmoid = rcp(1 + exp2(-(C2 + t*w2))),
//   t = clamp(x)+17.05.  One wave per unit, 8 buckets/lane.
// ---------------------------------------------------------------------------
__global__ __launch_bounds__(256) void build_table_kernel(
    const float* __restrict__ v, const float* __restrict__ b,
    float2* __restrict__ gtab) {
  const int lane = threadIdx.x & 63;
  const int wave = threadIdx.x >> 6;
  const int u = blockIdx.x * 4 + wave;
  if (u >= UNITS) return;

  const float* vu = v + u * NB;
  float w[8], pref[8];
  float run = 0.0f;
#pragma unroll
  for (int k = 0; k < 8; ++k) {
    const int j = lane * 8 + k;
    const float wv = (j < NB) ? fmaxf(vu[j], 0.0f) : 0.0f;
    w[k] = wv;
    pref[k] = run;  // exclusive within-lane prefix
    run += wv;
  }
  float s = run;    // inclusive wave scan of per-lane sums
#pragma unroll
  for (int d = 1; d < 64; d <<= 1) {
    const float o = __shfl_up(s, d, 64);
    if (lane >= d) s += o;
  }
  const float base = s - run;  // exclusive lane base
  const float off = RESIDUEF + b[u];
#pragma unroll
  for (int k = 0; k < 8; ++k) {
    const int j = lane * 8 + k;
    if (j < NB) {
      const float C = STEPF * (base + pref[k]) + off - (float)j * STEPF * w[k];
      gtab[u * NB + j] = make_float2(C * LOG2E, w[k] * LOG2E);
    }
  }
}

// ---------------------------------------------------------------------------
// Kernel 2: stream x -> out.  Per block: 32 units x 1024 rows, 1024 threads.
// LDS: 32-unit hot window, 32*257*8 = 65792 B -> exactly 2 blocks/CU
// (2*65792 = 131584 <= 163840), 32 waves/CU = full wave slots.
// Load mapping: lane l -> (row_off = l>>3, float4-col = l&7): each wave-load
// = 8 rows x 128 B aligned contiguous runs.
// 16 waves run independent depth-4-ring pipelines after a single barrier;
// the co-resident second block fills the other 4 wave slots per SIMD, hiding
// the ds_read/exp2 dependency-chain latency that capped us at 40% occupancy.
// ---------------------------------------------------------------------------
__global__ __launch_bounds__(THREADS, 8) void iso_main_kernel(
    const float* __restrict__ x, const float2* __restrict__ gtab,
    float* __restrict__ out) {
  __shared__ float2 tab[UPB * PADF2];  // 65792 B

  const int bu = blockIdx.x & 7;            // unit tile 0..7 (UPB=32)
  const int bb = blockIdx.x >> 3;           // batch tile 0..63
  const int u0 = bu * UPB;

  // ---- stage hot window: 32 units x 256 buckets, 8 entries/thread ----
#pragma unroll
  for (int i = threadIdx.x; i < UPB * WSZ; i += THREADS) {
    const int ul = i >> 8;                  // WSZ == 256
    const int j = i & (WSZ - 1);
    tab[ul * PADF2 + j] = gtab[(u0 + ul) * NB + WLO + j];
  }
  __syncthreads();                          // the only barrier

  // ---- stream: 8 chunks of 128 rows, depth-4 register ring ----
  const int tid = threadIdx.x;
  const int rowoff = tid >> 3;              // 0..127 within chunk
  const int col4 = tid & 7;                 // float4 col within 32-unit span
  const float4* __restrict__ x4 = reinterpret_cast<const float4*>(x);
  floatx4* __restrict__ o4 = reinterpret_cast<floatx4*>(out);
  // float4 linear index; row stride = 64 float4
  const int g0 = (bb * ROWS_PB + rowoff) * (UNITS / 4) + bu * (UPB / 4) + col4;
  const int gstep = 128 * (UNITS / 4);      // 128 rows per chunk
  const int qbase = (col4 * 4) * PADF2;     // LDS base for this thread's units

  float4 xv[RDEPTH];
#pragma unroll
  for (int c = 0; c < RDEPTH; ++c) xv[c] = x4[g0 + c * gstep];

#pragma unroll
  for (int c = 0; c < CHUNKS; ++c) {
    const float4 cur = xv[c & (RDEPTH - 1)];
    if (c + RDEPTH < CHUNKS)
      xv[c & (RDEPTH - 1)] = x4[g0 + (c + RDEPTH) * gstep];

    const float xs[4] = {cur.x, cur.y, cur.z, cur.w};
    float os[4];
#pragma unroll
    for (int k = 0; k < 4; ++k) {
      const float xc = fminf(fmaxf(xs[k], LBF + 1e-9f), UBF - 1e-9f);
      const float t = xc - LBF + STEPF;     // xc + 17.05, in (0, 25.05)
      int idx = (int)(t * 20.0f);           // 1/STEP == 20 exactly
      const unsigned iw = (unsigned)(idx - WLO);
      float2 cw;
      if (iw < WSZ) {                       // hot path: one ds_read_b64
        cw = tab[qbase + k * PADF2 + (int)iw];
      } else {                              // ~1e-7 of elements
        idx = idx < 0 ? 0 : (idx > NB - 1 ? NB - 1 : idx);
        cw = gtab[(u0 + col4 * 4 + k) * NB + idx];
      }
      const float l2 = fmaf(t, cw.y, cw.x); // log2e * logit
      const float e = __builtin_amdgcn_exp2f(-l2);
      os[k] = __builtin_amdgcn_rcpf(1.0f + e);
    }
    // out is write-once / never re-read: non-temporal store keeps the 64 MB
    // output stream from evicting x + gtab lines in L2/L3.
    floatx4 ov;
    ov.x = os[0]; ov.y = os[1]; ov.z = os[2]; ov.w = os[3];
    __builtin_nontemporal_store(ov, &o4[g0 + c * gstep]);
  }
}

extern "C" void kernel_launch(void* const* d_in, const int* in_sizes, int n_in,
                              void* d_out, int out_size, void* d_ws,
                              size_t ws_size, hipStream_t stream) {
  const float* x = (const float*)d_in[0];   // (65536, 256)
  const float* v = (const float*)d_in[1];   // (256, 501)
  const float* b = (const float*)d_in[2];   // (256,)
  float* out = (float*)d_out;               // (65536, 256)
  float2* gtab = (float2*)d_ws;             // 256*501*8 B = 1.03 MB

  build_table_kernel<<<64, 256, 0, stream>>>(v, b, gtab);

  const int rows = out_size / UNITS;                  // 65536
  const int grid = (UNITS / UPB) * (rows / ROWS_PB);  // 8 * 64 = 512
  iso_main_kernel<<<grid, THREADS, 0, stream>>>(x, gtab, out);
}